// Round 9
// baseline (860.013 us; speedup 1.0000x reference)
//
#include <hip/hip_runtime.h>
#include <hip/hip_bf16.h>
#include <stdint.h>

// Int8Linear: y[m,n] = scale[n] * sum_k x[m,k]*w[n,k] + bias[n]
// Device dtypes: x fp32 [8192,4096]; w int32 [11008,4096] (|v|<=127);
// scale/bias fp32 [11008]; out fp32 [8192,11008].
// Round 9: occupancy attack. 256x128 tile, 8 waves of 64x64 (acc=64 -> total
// regs <=128 -> 4 waves/SIMD), BK=32, dbuf-2 LDS = 48 KiB -> 2 blocks/CU.
// Inter-block TLP overlaps LDS-read pipe with MFMA pipe (r4..r8 all measured
// pipe-SUM serialization at 1 block/CU regardless of schedule). Conflict-free
// r4 swizzle (store s^((row>>1)&3) via inverse-swizzled gload source, read
// slot kg^((fr>>1)&3)). Free inner schedule, 1 barrier/tile. Bijective XCD
// swizzle over 2752 = 8*344 blocks.

#define K_DIM 4096
#define N_DIM 11008
#define M_DIM 8192

typedef __attribute__((ext_vector_type(8))) __bf16 bf16x8;
typedef __attribute__((ext_vector_type(4))) float f32x4;
typedef __attribute__((ext_vector_type(4))) int i32x4;

#define SB0 __builtin_amdgcn_sched_barrier(0)

__device__ __forceinline__ void gload_lds16(const void* g, void* l) {
  __builtin_amdgcn_global_load_lds(
      (const __attribute__((address_space(1))) void*)g,
      (__attribute__((address_space(3))) void*)l, 16, 0, 0);
}

// ---------------- prepass conversions (validated round 3) ----------------

__global__ void __launch_bounds__(256) wconv_kernel(const int* __restrict__ w,
                                                    __bf16* __restrict__ o,
                                                    int n8) {
  int i = blockIdx.x * 256 + threadIdx.x;
  if (i >= n8) return;
  const i32x4* src = (const i32x4*)w;
  i32x4 v0 = src[2 * i];
  i32x4 v1 = src[2 * i + 1];
  bf16x8 r;
#pragma unroll
  for (int j = 0; j < 4; ++j) {
    r[j]     = (__bf16)(float)v0[j];
    r[j + 4] = (__bf16)(float)v1[j];
  }
  *((bf16x8*)o + i) = r;
}

__global__ void __launch_bounds__(256) xconv_kernel(const float* __restrict__ x,
                                                    __bf16* __restrict__ o,
                                                    int n8) {
  int i = blockIdx.x * 256 + threadIdx.x;
  if (i >= n8) return;
  const f32x4* src = (const f32x4*)x;
  f32x4 v0 = src[2 * i];
  f32x4 v1 = src[2 * i + 1];
  bf16x8 r;
#pragma unroll
  for (int j = 0; j < 4; ++j) {
    r[j]     = (__bf16)v0[j];
    r[j + 4] = (__bf16)v1[j];
  }
  *((bf16x8*)o + i) = r;
}

// ---------------- 256x128 BK=32 GEMM, 2 blocks/CU ----------------

#define BM 256
#define BN 128
#define BK 32
#define KT (K_DIM / BK)   /* 128 */
#define MT (M_DIM / BM)   /* 32 */
#define NT2 (N_DIM / BN)  /* 86 */
#define NBLK (MT * NT2)   /* 2752 = 8*344 */
// LDS elems: A dbuf 2 x (256*32=8192), B dbuf 2 x (128*32=4096) => 24576 (48KB)
#define ATILE 8192
#define BBASE 16384

__global__ void __launch_bounds__(512, 4) gemm256x128_kernel(
    const __bf16* __restrict__ Xb, const __bf16* __restrict__ Wb,
    const float* __restrict__ scale, const float* __restrict__ bias,
    float* __restrict__ out) {
  __shared__ __align__(16) __bf16 lds[24576];  // 48 KiB

  const int tid = threadIdx.x;
  const int lane = tid & 63;
  const int wv = tid >> 6;        // 0..7
  const int wm = (wv >> 1) * 64;  // 4 M-waves
  const int wn = (wv & 1) * 64;   // 2 N-waves

  // T1: bijective XCD swizzle (2752 = 8*344)
  const int lid = blockIdx.x;
  const int swz = (lid & 7) * (NBLK / 8) + (lid >> 3);
  const int tm = swz / NT2;
  const int tn = swz - tm * NT2;
  const size_t m0 = (size_t)tm * BM;
  const size_t n0 = (size_t)tn * BN;

  // staging: one gload call = 512 lanes x 16B = 8 KB = 128 rows of 64 B.
  // local row = tid>>2, 16B-slot = tid&3. LDS[row][s] holds global k-chunk
  // s ^ ((row>>1)&3)  -> inverse-swizzled per-lane global source, wave-uniform
  // LDS base (HW writes lane i at base + i*16B).
  const size_t gOff = (size_t)(tid >> 2) * K_DIM +
                      (size_t)((((tid & 3) ^ ((tid >> 3) & 3))) << 3);
  const int ldsWv = wv * 512;  // wave-uniform elem offset within a call
  const __bf16* GA = Xb + m0 * K_DIM;
  const __bf16* GB = Wb + n0 * K_DIM;

#define STGA(LP, R0, TS)                                                  \
  gload_lds16(GA + (size_t)(R0) * K_DIM + (size_t)(TS) * BK + gOff,       \
              &lds[(LP) * ATILE + (R0) * 32 + ldsWv])
#define STGB(LP, TS)                                          \
  gload_lds16(GB + (size_t)(TS) * BK + gOff,                  \
              &lds[BBASE + (LP) * 4096 + ldsWv])

  // fragment reads (swizzled): slot = kg ^ ((fr>>1)&3); row&7 == fr&7.
  const int fr = lane & 15;
  const int kg = lane >> 4;
  const int srd = ((kg ^ ((fr >> 1) & 3)) << 3);
  const int aBase = (wm + fr) * 32;
  const int bBase = BBASE + (wn + fr) * 32;

#define RDA(LP, MF) \
  (*(const bf16x8*)&lds[(LP) * ATILE + aBase + (MF) * 512 + srd])
#define RDB(LP, NF) \
  (*(const bf16x8*)&lds[(LP) * 4096 + bBase + (NF) * 512 + srd])

  f32x4 acc[4][4];
#pragma unroll
  for (int m = 0; m < 4; ++m)
#pragma unroll
    for (int n = 0; n < 4; ++n) acc[m][n] = (f32x4){0.f, 0.f, 0.f, 0.f};

  // prologue: stage tile 0 into buffer 0
  STGA(0, 0, 0);
  STGA(0, 128, 0);
  STGB(0, 0);
  asm volatile("s_waitcnt vmcnt(0)" ::: "memory");
  SB0;
  __builtin_amdgcn_s_barrier();

  for (int t = 0; t < KT; ++t) {
    const int p = t & 1;
    const int np = p ^ 1;

    // issue next-tile staging first (3 DMAs), pinned before compute
    if (t + 1 < KT) {
      STGA(np, 0, t + 1);
      STGA(np, 128, t + 1);
      STGB(np, t + 1);
    }
    SB0;

    // compute tile t from buffer p — compiler-scheduled
    bf16x8 b0 = RDB(p, 0), b1 = RDB(p, 1), b2 = RDB(p, 2), b3 = RDB(p, 3);
#pragma unroll
    for (int mf = 0; mf < 4; ++mf) {
      bf16x8 a = RDA(p, mf);
      acc[mf][0] = __builtin_amdgcn_mfma_f32_16x16x32_bf16(a, b0, acc[mf][0], 0, 0, 0);
      acc[mf][1] = __builtin_amdgcn_mfma_f32_16x16x32_bf16(a, b1, acc[mf][1], 0, 0, 0);
      acc[mf][2] = __builtin_amdgcn_mfma_f32_16x16x32_bf16(a, b2, acc[mf][2], 0, 0, 0);
      acc[mf][3] = __builtin_amdgcn_mfma_f32_16x16x32_bf16(a, b3, acc[mf][3], 0, 0, 0);
    }

    asm volatile("s_waitcnt lgkmcnt(0)" ::: "memory");
    asm volatile("s_waitcnt vmcnt(0)" ::: "memory");
    __builtin_amdgcn_s_barrier();
  }

  // epilogue: C/D layout col=lane&15, row=(lane>>4)*4+reg (r3-validated)
  const int cc = lane & 15;
  const int rr = (lane >> 4) * 4;
#pragma unroll
  for (int nf = 0; nf < 4; ++nf) {
    const int col = (int)n0 + wn + nf * 16 + cc;
    const float sc = scale[col];
    const float bi = bias[col];
#pragma unroll
    for (int mf = 0; mf < 4; ++mf) {
      const size_t rowb = m0 + wm + mf * 16 + rr;
#pragma unroll
      for (int r = 0; r < 4; ++r) {
        out[(rowb + r) * N_DIM + col] = acc[mf][nf][r] * sc + bi;
      }
    }
  }
#undef STGA
#undef STGB
#undef RDA
#undef RDB
}

// ---------------- fallback 128x128 kernel (round-3 validated) ----------------

#define FBM 128
#define FBN 128
#define FBK 32
#define FNT (N_DIM / FBN) /* 86 */
#define FMT (M_DIM / FBM) /* 64 */

__device__ __forceinline__ bf16x8 cvt8f(f32x4 a, f32x4 b) {
  bf16x8 h;
#pragma unroll
  for (int j = 0; j < 4; ++j) {
    h[j] = (__bf16)a[j];
    h[j + 4] = (__bf16)b[j];
  }
  return h;
}

__device__ __forceinline__ bf16x8 cvt8i(i32x4 a, i32x4 b) {
  bf16x8 h;
#pragma unroll
  for (int j = 0; j < 4; ++j) {
    h[j] = (__bf16)(float)a[j];
    h[j + 4] = (__bf16)(float)b[j];
  }
  return h;
}

template <int MODE>  // 1: W preconv; 2: no workspace
__global__ void __launch_bounds__(256, 2) gemm_fb_kernel(
    const float* __restrict__ X, const __bf16* __restrict__ Wb,
    const int* __restrict__ Wq, const float* __restrict__ scale,
    const float* __restrict__ bias, float* __restrict__ out) {
  __shared__ __align__(16) __bf16 As[FBM * FBK];
  __shared__ __align__(16) __bf16 Bs[FBN * FBK];

  const int tid = threadIdx.x;
  const int lane = tid & 63;
  const int wv = tid >> 6;

  const int lid = blockIdx.x;
  const int swz = (lid & 7) * ((FMT * FNT) >> 3) + (lid >> 3);
  const int tm = swz / FNT;
  const int tn = swz - tm * FNT;
  const int m0 = tm * FBM;
  const int n0 = tn * FBN;

  const int e0 = wv * 512 + lane * 8;
  const int e1 = e0 + 2048;
  const int r0 = e0 >> 5, c0 = e0 & 31;
  const int r1 = e1 >> 5, c1 = e1 & 31;

  f32x4 acc[4][4];
#pragma unroll
  for (int m = 0; m < 4; ++m)
#pragma unroll
    for (int n = 0; n < 4; ++n) acc[m][n] = (f32x4){0.f, 0.f, 0.f, 0.f};

  const int wm = (wv >> 1) * 64;
  const int wn = (wv & 1) * 64;
  const int fr = lane & 15;
  const int kc = (lane >> 4) * 8;

  const float* srcAf0 = X + (size_t)(m0 + r0) * K_DIM + c0;
  const float* srcAf1 = X + (size_t)(m0 + r1) * K_DIM + c1;
  const __bf16* srcBb0 = Wb + (size_t)(n0 + r0) * K_DIM + c0;
  const __bf16* srcBb1 = Wb + (size_t)(n0 + r1) * K_DIM + c1;
  const int* srcQ0 = Wq + (size_t)(n0 + r0) * K_DIM + c0;
  const int* srcQ1 = Wq + (size_t)(n0 + r1) * K_DIM + c1;

  for (int k0 = 0; k0 < K_DIM; k0 += FBK) {
    f32x4 a0 = *(const f32x4*)(srcAf0 + k0);
    f32x4 a1 = *(const f32x4*)(srcAf0 + k0 + 4);
    f32x4 a2 = *(const f32x4*)(srcAf1 + k0);
    f32x4 a3 = *(const f32x4*)(srcAf1 + k0 + 4);
    if constexpr (MODE == 1) {
      gload_lds16(srcBb0 + k0, &Bs[e0]);
      gload_lds16(srcBb1 + k0, &Bs[e1]);
    } else {
      i32x4 q0 = *(const i32x4*)(srcQ0 + k0);
      i32x4 q1 = *(const i32x4*)(srcQ0 + k0 + 4);
      i32x4 q2 = *(const i32x4*)(srcQ1 + k0);
      i32x4 q3 = *(const i32x4*)(srcQ1 + k0 + 4);
      *(bf16x8*)&Bs[e0] = cvt8i(q0, q1);
      *(bf16x8*)&Bs[e1] = cvt8i(q2, q3);
    }
    *(bf16x8*)&As[e0] = cvt8f(a0, a1);
    *(bf16x8*)&As[e1] = cvt8f(a2, a3);
    __syncthreads();

    bf16x8 a[4], b[4];
#pragma unroll
    for (int m = 0; m < 4; ++m)
      a[m] = *(const bf16x8*)&As[(wm + m * 16 + fr) * FBK + kc];
#pragma unroll
    for (int n = 0; n < 4; ++n)
      b[n] = *(const bf16x8*)&Bs[(wn + n * 16 + fr) * FBK + kc];
#pragma unroll
    for (int m = 0; m < 4; ++m)
#pragma unroll
      for (int n = 0; n < 4; ++n)
        acc[m][n] = __builtin_amdgcn_mfma_f32_16x16x32_bf16(a[m], b[n],
                                                            acc[m][n], 0, 0, 0);
    __syncthreads();
  }

  const int cc = lane & 15;
  const int rr = (lane >> 4) * 4;
#pragma unroll
  for (int n = 0; n < 4; ++n) {
    const int col = n0 + wn + n * 16 + cc;
    const float sc = scale[col];
    const float bi = bias[col];
#pragma unroll
    for (int m = 0; m < 4; ++m) {
      const int rowb = m0 + wm + m * 16 + rr;
#pragma unroll
      for (int r = 0; r < 4; ++r) {
        out[(size_t)(rowb + r) * N_DIM + col] = acc[m][n][r] * sc + bi;
      }
    }
  }
}

// ---------------- launch ----------------

extern "C" void kernel_launch(void* const* d_in, const int* in_sizes, int n_in,
                              void* d_out, int out_size, void* d_ws, size_t ws_size,
                              hipStream_t stream) {
  const float* X = (const float*)d_in[0];
  const int* Wq = (const int*)d_in[1];
  const float* scale = (const float*)d_in[2];
  const float* bias = (const float*)d_in[3];
  float* out = (float*)d_out;

  const size_t wbytes = (size_t)N_DIM * K_DIM * sizeof(__bf16);  // 90,177,536
  const size_t xbytes = (size_t)M_DIM * K_DIM * sizeof(__bf16);  // 67,108,864
  const int n8w = (N_DIM * K_DIM) / 8;
  const int n8x = (M_DIM * K_DIM) / 8;

  if (ws_size >= wbytes + xbytes) {
    __bf16* Wb = (__bf16*)d_ws;
    __bf16* Xb = (__bf16*)((char*)d_ws + wbytes);
    wconv_kernel<<<dim3((n8w + 255) / 256), dim3(256), 0, stream>>>(Wq, Wb, n8w);
    xconv_kernel<<<dim3((n8x + 255) / 256), dim3(256), 0, stream>>>(X, Xb, n8x);
    gemm256x128_kernel<<<dim3(NBLK), dim3(512), 0, stream>>>(Xb, Wb, scale, bias, out);
  } else if (ws_size >= wbytes) {
    __bf16* Wb = (__bf16*)d_ws;
    wconv_kernel<<<dim3((n8w + 255) / 256), dim3(256), 0, stream>>>(Wq, Wb, n8w);
    gemm_fb_kernel<1><<<dim3(FMT * FNT), dim3(256), 0, stream>>>(
        X, Wb, Wq, scale, bias, out);
  } else {
    gemm_fb_kernel<2><<<dim3(FMT * FNT), dim3(256), 0, stream>>>(
        X, nullptr, Wq, scale, bias, out);
  }
}